// Round 2
// baseline (233.880 us; speedup 1.0000x reference)
//
#include <hip/hip_runtime.h>

typedef __bf16 bfx8 __attribute__((ext_vector_type(8)));
typedef float fx4 __attribute__((ext_vector_type(4)));
typedef unsigned short us4 __attribute__((ext_vector_type(4)));
typedef unsigned short us8 __attribute__((ext_vector_type(8)));

#define NNODES 90
#define NPAD   96
#define HF     128
#define NGRAPH 512
#define EPG    1440                 // edges per graph
#define ETOT   (NGRAPH*EPG)
#define KTOT   34560                // 90*384
#define NKTOT  1080                 // KTOT/32
#define KSPLIT 45
#define KSTEPS (NKTOT/KSPLIT)       // 24

__device__ __forceinline__ float bf2f(unsigned short s){
  union { unsigned u; float f; } v; v.u = ((unsigned)s)<<16; return v.f;
}
__device__ __forceinline__ unsigned short f2bf(float f){
  union { float f; unsigned u; } v; v.f = f;
  return (unsigned short)((v.u + 0x7FFFu + ((v.u>>16)&1u)) >> 16);
}

// ---- dtype probe: flags[0]=1 if floats are f32 (else bf16); flags[1]=1 if ints are i64
__global__ void probe_kern(const unsigned short* __restrict__ x,
                           const int* __restrict__ ei,
                           int* __restrict__ flags){
  if (threadIdx.x != 0 || blockIdx.x != 0) return;
  int weird = 0;
  for (int i = 0; i < 1024; ++i) {
    unsigned u = x[i];
    int ex = (u >> 7) & 0xFF;
    if (ex > 157 || (ex < 97 && u != 0)) weird++;
  }
  flags[0] = (weird > 100) ? 1 : 0;
  long long ss = 0;
  for (int k = 0; k < 64; ++k) {
    int v = ei[2*k + 1];
    ss += (v < 0) ? -(long long)v : (long long)v;
  }
  flags[1] = (ss == 0) ? 1 : 0;
}

// ---- pack W [K][128] -> B-fragment layout [nt(8)][ks(nK)][lane(64)][j(8)]
__global__ void pack_w_kern(const unsigned short* __restrict__ W,
                            unsigned short* __restrict__ out, int K, int nK,
                            const int* __restrict__ flags){
  int t = blockIdx.x*blockDim.x + threadIdx.x;
  int total = 8*nK*64;
  if (t >= total) return;
  const int f32f = flags[0];
  const float* Wf = (const float*)W;
  int lane = t & 63;
  int ks = (t>>6) % nK;
  int nt = (t>>6) / nK;
  int n  = nt*16 + (lane&15);
  int k0 = ks*32 + (lane>>4)*8;
  unsigned short v[8];
#pragma unroll
  for (int j=0;j<8;j++){
    int k=k0+j;
    unsigned short val = 0;
    if (k < K) val = f32f ? f2bf(Wf[k*128+n]) : W[k*128+n];
    v[j] = val;
  }
  unsigned short* o = out + ((nt*nK+ks)*64 + lane)*8;
#pragma unroll
  for (int j=0;j<8;j++) o[j]=v[j];
}

// ---- pack lin1_W [34560][64] -> [nt(4)][ks(1080)][lane(64)][j(8)]
__global__ void pack_lin1_kern(const unsigned short* __restrict__ W,
                               unsigned short* __restrict__ out,
                               const int* __restrict__ flags){
  __shared__ __align__(16) unsigned short tile[32*64];
  int ks = blockIdx.x;       // 0..1079  (32 k-rows each)
  int t  = threadIdx.x;      // 256
  const int f32f = flags[0];
  if (f32f) {
    const float* Wf = (const float*)W;
#pragma unroll
    for (int j=0;j<8;j++) tile[t*8+j] = f2bf(Wf[ks*32*64 + t*8 + j]);
  } else {
    us8 v = *(const us8*)&W[ks*32*64 + t*8];   // coalesced 16B per thread
    *(us8*)&tile[t*8] = v;
  }
  __syncthreads();
  int lane = t & 63;
  int nt = t >> 6;           // 0..3
  int n  = nt*16 + (lane&15);
  int kq = (lane>>4)*8;
  us8 v;
#pragma unroll
  for (int j=0;j<8;j++) v[j] = tile[(kq+j)*64 + n];
  *(us8*)&out[((nt*NKTOT + ks)*64 + lane)*8] = v;
}

// ---- per-graph GCN: dense normalized adjacency in LDS, 3x (MFMA mm + MFMA agg)
__global__ __launch_bounds__(256) void gcn_layers_kern(
    const unsigned short* __restrict__ x,
    const unsigned short* __restrict__ eattr,
    const int* __restrict__ ei,
    const unsigned short* __restrict__ w1p,
    const unsigned short* __restrict__ w2p,
    const unsigned short* __restrict__ w3p,
    const unsigned short* __restrict__ b1,
    const unsigned short* __restrict__ b2,
    const unsigned short* __restrict__ b3,
    unsigned short* __restrict__ xc,
    const int* __restrict__ flags)
{
  __shared__ __align__(16) char smem[65280];
  unsigned short* Abf = (unsigned short*)smem;
  unsigned short* H   = (unsigned short*)(smem + 17280);
  unsigned short* Tt  = (unsigned short*)(smem + 40320);
  float* Af  = (float*)(smem + 17280);
  float* deg = (float*)(smem + 64896);

  const int g = blockIdx.x;
  const int tid = threadIdx.x;
  const int lane = tid & 63, wave = tid >> 6;
  const int q = lane >> 4, r = lane & 15;
  const int eb = g*EPG;
  const int nb = g*NNODES;
  const int f32f = flags[0];
  const int i64f = flags[1];
  const float* xf = (const float*)x;
  const float* eaf = (const float*)eattr;
  const long long* e64 = (const long long*)ei;

  // phase 0: degree + dense A
  for (int i = tid; i < NNODES; i += 256) deg[i] = 1.0f;         // self-loop w=1
  for (int i = tid; i < NNODES*NPAD; i += 256) Af[i] = 0.0f;
  __syncthreads();
  for (int e = tid; e < EPG; e += 256) {
    int d = i64f ? (int)e64[ETOT + eb + e] : ei[ETOT + eb + e];
    float w = f32f ? eaf[eb + e] : bf2f(eattr[eb + e]);
    atomicAdd(&deg[d - nb], w);
  }
  __syncthreads();
  for (int i = tid; i < NNODES; i += 256) deg[i] = rsqrtf(deg[i]); // deg>=1 always
  __syncthreads();
  for (int e = tid; e < EPG; e += 256) {
    int s = (i64f ? (int)e64[eb + e] : ei[eb + e]) - nb;
    int d = (i64f ? (int)e64[ETOT + eb + e] : ei[ETOT + eb + e]) - nb;
    float w = f32f ? eaf[eb + e] : bf2f(eattr[eb + e]);
    atomicAdd(&Af[d*NPAD + s], deg[d]*w*deg[s]);
  }
  for (int i = tid; i < NNODES; i += 256) atomicAdd(&Af[i*NPAD + i], deg[i]*deg[i]);
  __syncthreads();
  for (int i = tid; i < NNODES*NPAD; i += 256) Abf[i] = f2bf(Af[i]);
  __syncthreads();
  // load X into H (cols 90..95 zeroed to be NaN-safe; K-pad rows of W1pack are zero)
  for (int i = tid; i < NNODES*90; i += 256) {
    int node = i/90, f = i - node*90;
    H[node*HF + f] = f32f ? f2bf(xf[(nb + node)*90 + f]) : x[(nb + node)*90 + f];
  }
  for (int i = tid; i < NNODES*6; i += 256) {
    int node = i/6, c = i - node*6;
    H[node*HF + 90 + c] = 0;
  }
  __syncthreads();

#pragma unroll
  for (int l = 0; l < 3; ++l) {
    const unsigned short* wpk  = (l==0)? w1p : (l==1)? w2p : w3p;
    const unsigned short* bias = (l==0)? b1 : (l==1)? b2 : b3;
    const int nK = (l==0)? 3 : 4;

    // mm1: Tt = (H @ W)^T.  wave handles nt {2w,2w+1}, all 6 m-tiles.
    for (int mt = 0; mt < 6; ++mt) {
      int row = mt*16 + r; if (row > 89) row = 89;   // clamp; garbage rows killed by A's zero cols
      bfx8 af[4];
#pragma unroll
      for (int ks = 0; ks < 4; ++ks)
        if (ks < nK) af[ks] = *(const bfx8*)(const void*)&H[row*HF + ks*32 + q*8];
#pragma unroll
      for (int ni = 0; ni < 2; ++ni) {
        int nt = wave*2 + ni;
        fx4 acc = {0.f,0.f,0.f,0.f};
#pragma unroll
        for (int ks = 0; ks < 4; ++ks)
          if (ks < nK) {
            bfx8 bf = *(const bfx8*)(const void*)&wpk[((nt*nK + ks)*64 + lane)*8];
            acc = __builtin_amdgcn_mfma_f32_16x16x32_bf16(af[ks], bf, acc, 0,0,0);
          }
        us4 o;
#pragma unroll
        for (int i2=0;i2<4;i2++) o[i2] = f2bf(acc[i2]);
        // D[node=q*4+i][feat=r] -> Tt[feat][node], 4 consecutive bf16
        *(us4*)&Tt[(nt*16 + r)*NPAD + mt*16 + q*4] = o;
      }
    }
    __syncthreads();

    // agg: H = relu(A@T + b), computed as S^T = T^T @ A^T (all reads contiguous)
#pragma unroll
    for (int fi = 0; fi < 2; ++fi) {
      int ft = wave*2 + fi;                 // feature tile (8 total / 4 waves)
      bfx8 af[3];
#pragma unroll
      for (int ks = 0; ks < 3; ++ks)
        af[ks] = *(const bfx8*)(const void*)&Tt[(ft*16 + r)*NPAD + ks*32 + q*8];
      float bv[4];
#pragma unroll
      for (int i2=0;i2<4;i2++){
        int bidx = ft*16 + q*4 + i2;
        bv[i2] = f32f ? ((const float*)bias)[bidx] : bf2f(bias[bidx]);
      }
      for (int nt = 0; nt < 6; ++nt) {
        int arow = nt*16 + r; if (arow > 89) arow = 89;
        fx4 acc = {0.f,0.f,0.f,0.f};
#pragma unroll
        for (int ks = 0; ks < 3; ++ks) {
          bfx8 bfr = *(const bfx8*)(const void*)&Abf[arow*NPAD + ks*32 + q*8];
          acc = __builtin_amdgcn_mfma_f32_16x16x32_bf16(af[ks], bfr, acc, 0,0,0);
        }
        int m = nt*16 + r;                  // node (C col)
        if (m < NNODES) {
          us4 o;
#pragma unroll
          for (int i2=0;i2<4;i2++){
            float v = acc[i2] + bv[i2];
            o[i2] = f2bf(v > 0.f ? v : 0.f);
          }
          *(us4*)&H[m*HF + ft*16 + q*4] = o;
        }
      }
    }
    __syncthreads();

    // stream H -> xc[:, l*128 : (l+1)*128]
    for (int i = tid*4; i < NNODES*HF; i += 256*4) {
      us4 v = *(const us4*)&H[i];
      int node = i >> 7, f = i & 127;
      *(us4*)&xc[(nb + node)*384 + l*128 + f] = v;
    }
    __syncthreads();
  }
}

// ---- head GEMM: [512,34560]@[34560,64], split-K=45, bf16 MFMA, fp32 atomic reduce
__global__ __launch_bounds__(256) void gemm2_kern(
    const unsigned short* __restrict__ z,   // xc viewed as [512][34560]
    const unsigned short* __restrict__ wp,  // packed lin1_W
    float* __restrict__ accf)               // [512][64]
{
  __shared__ __align__(16) unsigned short zt[32*64];  // [32 rows][64 k], XOR-swizzled 16B chunks
  int mb = blockIdx.x % 16;
  int kb = blockIdx.x / 16;
  int tid = threadIdx.x;
  int lane = tid & 63, wave = tid >> 6;
  int q = lane >> 4, r = lane & 15;
  int mt = wave >> 1;            // 0..1
  int nt0 = (wave & 1)*2;        // 0 or 2
  int m0 = mb*32;

  fx4 acc0 = {0,0,0,0}, acc1 = {0,0,0,0};
  int Lm = tid >> 3, Lc = tid & 7;
  int Cc = Lc ^ (Lm & 7);        // chunk stored at position Lc
  int arow = mt*16 + r;

  for (int it = 0; it < KSTEPS/2; ++it) {   // 12 iters x 64 k
    int ks0 = kb*KSTEPS + it*2;
    int kbase = ks0*32;
    {
      us8 v = *(const us8*)&z[(m0+Lm)*KTOT + kbase + Cc*8];
      *(us8*)&zt[Lm*64 + Lc*8] = v;
    }
    __syncthreads();
#pragma unroll
    for (int ks2 = 0; ks2 < 2; ++ks2) {
      int c = ks2*4 + q;
      bfx8 af = *(const bfx8*)(const void*)&zt[arow*64 + ((c ^ (arow & 7))*8)];
      int ksg = ks0 + ks2;
      bfx8 bA = *(const bfx8*)(const void*)&wp[(((nt0+0)*NKTOT + ksg)*64 + lane)*8];
      bfx8 bB = *(const bfx8*)(const void*)&wp[(((nt0+1)*NKTOT + ksg)*64 + lane)*8];
      acc0 = __builtin_amdgcn_mfma_f32_16x16x32_bf16(af, bA, acc0, 0,0,0);
      acc1 = __builtin_amdgcn_mfma_f32_16x16x32_bf16(af, bB, acc1, 0,0,0);
    }
    __syncthreads();
  }
#pragma unroll
  for (int i2 = 0; i2 < 4; ++i2) {
    int row = m0 + mt*16 + q*4 + i2;
    atomicAdd(&accf[row*64 + (nt0+0)*16 + r], acc0[i2]);
    atomicAdd(&accf[row*64 + (nt0+1)*16 + r], acc1[i2]);
  }
}

// ---- head: bias+relu, lin2, log_softmax (C=2), dtype-adaptive out
__global__ void head_kern(const float* __restrict__ accf,
                          const unsigned short* __restrict__ l1b,
                          const unsigned short* __restrict__ l2w,
                          const unsigned short* __restrict__ l2b,
                          unsigned short* __restrict__ out,
                          const int* __restrict__ flags)
{
  int gph = blockIdx.x*blockDim.x + threadIdx.x;
  if (gph >= NGRAPH) return;
  const int f32f = flags[0];
  const float* l1bf = (const float*)l1b;
  const float* l2wf = (const float*)l2w;
  const float* l2bf = (const float*)l2b;
  float l0 = f32f ? l2bf[0] : bf2f(l2b[0]);
  float l1 = f32f ? l2bf[1] : bf2f(l2b[1]);
  for (int j = 0; j < 64; ++j) {
    float h = accf[gph*64 + j] + (f32f ? l1bf[j] : bf2f(l1b[j]));
    h = h > 0.f ? h : 0.f;
    l0 += h * (f32f ? l2wf[2*j]   : bf2f(l2w[2*j]));
    l1 += h * (f32f ? l2wf[2*j+1] : bf2f(l2w[2*j+1]));
  }
  float mx = fmaxf(l0, l1);
  float lse = mx + logf(expf(l0-mx) + expf(l1-mx));
  if (f32f) {
    ((float*)out)[gph*2]   = l0 - lse;
    ((float*)out)[gph*2+1] = l1 - lse;
  } else {
    out[gph*2]   = f2bf(l0 - lse);
    out[gph*2+1] = f2bf(l1 - lse);
  }
}

extern "C" void kernel_launch(void* const* d_in, const int* in_sizes, int n_in,
                              void* d_out, int out_size, void* d_ws, size_t ws_size,
                              hipStream_t stream)
{
  const unsigned short* x   = (const unsigned short*)d_in[0];
  const unsigned short* ea  = (const unsigned short*)d_in[1];
  const unsigned short* W1  = (const unsigned short*)d_in[2];
  const unsigned short* b1  = (const unsigned short*)d_in[3];
  const unsigned short* W2  = (const unsigned short*)d_in[4];
  const unsigned short* b2  = (const unsigned short*)d_in[5];
  const unsigned short* W3  = (const unsigned short*)d_in[6];
  const unsigned short* b3  = (const unsigned short*)d_in[7];
  const unsigned short* L1W = (const unsigned short*)d_in[8];
  const unsigned short* L1b = (const unsigned short*)d_in[9];
  const unsigned short* L2W = (const unsigned short*)d_in[10];
  const unsigned short* L2b = (const unsigned short*)d_in[11];
  const int* ei             = (const int*)d_in[12];
  unsigned short* out       = (unsigned short*)d_out;

  char* ws = (char*)d_ws;
  unsigned short* xc  = (unsigned short*)(ws);             // 35,389,440 B
  unsigned short* l1p = (unsigned short*)(ws + 35389440);  //  4,423,680 B
  unsigned short* w1p = (unsigned short*)(ws + 39813120);  //     24,576 B
  unsigned short* w2p = (unsigned short*)(ws + 39837696);  //     32,768 B
  unsigned short* w3p = (unsigned short*)(ws + 39870464);  //     32,768 B
  float* accf         = (float*)(ws + 39903232);           //    131,072 B
  int* flags          = (int*)(ws + 40034304);             //        256 B

  probe_kern<<<1, 64, 0, stream>>>(x, ei, flags);
  pack_w_kern<<<6, 256, 0, stream>>>(W1, w1p, 90, 3, flags);
  pack_w_kern<<<8, 256, 0, stream>>>(W2, w2p, 128, 4, flags);
  pack_w_kern<<<8, 256, 0, stream>>>(W3, w3p, 128, 4, flags);
  pack_lin1_kern<<<NKTOT, 256, 0, stream>>>(L1W, l1p, flags);
  gcn_layers_kern<<<NGRAPH, 256, 0, stream>>>(x, ea, ei, w1p, w2p, w3p,
                                              b1, b2, b3, xc, flags);
  hipMemsetAsync(accf, 0, NGRAPH*64*sizeof(float), stream);
  gemm2_kern<<<16*KSPLIT, 256, 0, stream>>>(xc, l1p, accf);
  head_kern<<<2, 256, 0, stream>>>(accf, L1b, L2W, L2b, out, flags);
}

// Round 3
// 171.543 us; speedup vs baseline: 1.3634x; 1.3634x over previous
//
#include <hip/hip_runtime.h>

typedef __bf16 bfx8 __attribute__((ext_vector_type(8)));
typedef float fx4 __attribute__((ext_vector_type(4)));
typedef unsigned short us4 __attribute__((ext_vector_type(4)));
typedef unsigned short us8 __attribute__((ext_vector_type(8)));

#define NNODES 90
#define NPAD   96
#define HF     128
#define NGRAPH 512
#define EPG    1440                 // edges per graph
#define ETOT   (NGRAPH*EPG)
#define KTOT   34560                // 90*384
#define NKTOT  1080                 // KTOT/32
#define KSPLIT 45
#define KSTEPS (NKTOT/KSPLIT)       // 24

__device__ __forceinline__ float bf2f(unsigned short s){
  union { unsigned u; float f; } v; v.u = ((unsigned)s)<<16; return v.f;
}
__device__ __forceinline__ unsigned short f2bf(float f){
  union { float f; unsigned u; } v; v.f = f;
  return (unsigned short)((v.u + 0x7FFFu + ((v.u>>16)&1u)) >> 16);
}

// ---- dtype probe (parallel): flags[0]=1 if floats are f32; flags[1]=1 if ints are i64
__global__ void probe_kern(const unsigned short* __restrict__ x,
                           const int* __restrict__ ei,
                           int* __restrict__ flags){
  int t = threadIdx.x;               // 256
  __shared__ int sw[4];
  __shared__ long long se;
  int weird = 0;
  for (int i = t; i < 1024; i += 256) {
    unsigned u = x[i];
    int ex = (u >> 7) & 0xFF;
    if (ex > 157 || (ex < 97 && u != 0)) weird++;
  }
  for (int off = 32; off; off >>= 1) weird += __shfl_down(weird, off);
  if ((t & 63) == 0) sw[t >> 6] = weird;
  long long ss = 0;
  if (t < 64) { int v = ei[2*t + 1]; ss = (v < 0) ? -(long long)v : (long long)v; }
  for (int off = 32; off; off >>= 1) ss += __shfl_down(ss, off);
  if (t == 0) se = ss;
  __syncthreads();
  if (t == 0) {
    flags[0] = ((sw[0]+sw[1]+sw[2]+sw[3]) > 100) ? 1 : 0;
    flags[1] = (se == 0) ? 1 : 0;
  }
}

// ---- fused pack of W1/W2/W3 [K][128] -> B-frag layout [nt(8)][ks(nK)][lane(64)][j(8)]
__global__ void pack_w3_kern(const unsigned short* __restrict__ W1,
                             const unsigned short* __restrict__ W2,
                             const unsigned short* __restrict__ W3,
                             unsigned short* __restrict__ o1,
                             unsigned short* __restrict__ o2,
                             unsigned short* __restrict__ o3,
                             const int* __restrict__ flags){
  int b = blockIdx.x;
  const unsigned short* W; unsigned short* out; int K, nK, t;
  if (b < 6)       { W = W1; out = o1; K = 90;  nK = 3; t = b*256 + threadIdx.x; }
  else if (b < 14) { W = W2; out = o2; K = 128; nK = 4; t = (b-6)*256 + threadIdx.x; }
  else             { W = W3; out = o3; K = 128; nK = 4; t = (b-14)*256 + threadIdx.x; }
  const int f32f = flags[0];
  const float* Wf = (const float*)W;
  int lane = t & 63;
  int ks = (t>>6) % nK;
  int nt = (t>>6) / nK;
  int n  = nt*16 + (lane&15);
  int k0 = ks*32 + (lane>>4)*8;
  unsigned short v[8];
#pragma unroll
  for (int j=0;j<8;j++){
    int k=k0+j;
    unsigned short val = 0;
    if (k < K) val = f32f ? f2bf(Wf[k*128+n]) : W[k*128+n];
    v[j] = val;
  }
  unsigned short* o = out + ((nt*nK+ks)*64 + lane)*8;
#pragma unroll
  for (int j=0;j<8;j++) o[j]=v[j];
}

// ---- pack lin1_W [34560][64] -> [nt(4)][ks(1080)][lane(64)][j(8)]
__global__ void pack_lin1_kern(const unsigned short* __restrict__ W,
                               unsigned short* __restrict__ out,
                               const int* __restrict__ flags){
  __shared__ __align__(16) unsigned short tile[32*64];
  int ks = blockIdx.x;       // 0..1079  (32 k-rows each)
  int t  = threadIdx.x;      // 256
  const int f32f = flags[0];
  if (f32f) {
    const float* Wf = (const float*)W;
#pragma unroll
    for (int j=0;j<8;j++) tile[t*8+j] = f2bf(Wf[ks*32*64 + t*8 + j]);
  } else {
    us8 v = *(const us8*)&W[ks*32*64 + t*8];
    *(us8*)&tile[t*8] = v;
  }
  __syncthreads();
  int lane = t & 63;
  int nt = t >> 6;           // 0..3
  int n  = nt*16 + (lane&15);
  int kq = (lane>>4)*8;
  us8 v;
#pragma unroll
  for (int j=0;j<8;j++) v[j] = tile[(kq+j)*64 + n];
  *(us8*)&out[((nt*NKTOT + ks)*64 + lane)*8] = v;
}

// ---- per-graph GCN, 512 threads (8 waves): dense normalized A in LDS,
//      3x (MFMA mm + MFMA agg). Wave w owns nt=w (mm1) / ft=w (agg).
__global__ __launch_bounds__(512) void gcn_layers_kern(
    const unsigned short* __restrict__ x,
    const unsigned short* __restrict__ eattr,
    const int* __restrict__ ei,
    const unsigned short* __restrict__ w1p,
    const unsigned short* __restrict__ w2p,
    const unsigned short* __restrict__ w3p,
    const unsigned short* __restrict__ b1,
    const unsigned short* __restrict__ b2,
    const unsigned short* __restrict__ b3,
    unsigned short* __restrict__ xc,
    const int* __restrict__ flags)
{
  __shared__ __align__(16) char smem[65280];
  unsigned short* Abf = (unsigned short*)smem;
  unsigned short* H   = (unsigned short*)(smem + 17280);
  unsigned short* Tt  = (unsigned short*)(smem + 40320);
  float* Af  = (float*)(smem + 17280);
  float* deg = (float*)(smem + 64896);

  const int g = blockIdx.x;
  const int tid = threadIdx.x;
  const int lane = tid & 63, wave = tid >> 6;
  const int q = lane >> 4, r = lane & 15;
  const int eb = g*EPG;
  const int nb = g*NNODES;
  const int f32f = flags[0];
  const int i64f = flags[1];
  const float* xf = (const float*)x;
  const float* eaf = (const float*)eattr;
  const long long* e64 = (const long long*)ei;

  // phase 0: degree + dense A (LDS atomics)
  for (int i = tid; i < NNODES; i += 512) deg[i] = 1.0f;          // self-loop w=1
  for (int i = tid; i < NNODES*NPAD; i += 512) Af[i] = 0.0f;
  __syncthreads();
  for (int e = tid; e < EPG; e += 512) {
    int d = (i64f ? (int)e64[ETOT + eb + e] : ei[ETOT + eb + e]) - nb;
    float w = f32f ? eaf[eb + e] : bf2f(eattr[eb + e]);
    atomicAdd(&deg[d], w);
  }
  __syncthreads();
  for (int i = tid; i < NNODES; i += 512) deg[i] = rsqrtf(deg[i]); // deg>=1 always
  __syncthreads();
  for (int e = tid; e < EPG; e += 512) {
    int s = (i64f ? (int)e64[eb + e] : ei[eb + e]) - nb;
    int d = (i64f ? (int)e64[ETOT + eb + e] : ei[ETOT + eb + e]) - nb;
    float w = f32f ? eaf[eb + e] : bf2f(eattr[eb + e]);
    atomicAdd(&Af[d*NPAD + s], deg[d]*w*deg[s]);
  }
  for (int i = tid; i < NNODES; i += 512) atomicAdd(&Af[i*NPAD + i], deg[i]*deg[i]);
  __syncthreads();
  for (int i = tid; i < NNODES*NPAD; i += 512) Abf[i] = f2bf(Af[i]);
  __syncthreads();
  // load X into H (cols 90..95 zeroed: NaN-safe K-pad)
  for (int i = tid; i < NNODES*90; i += 512) {
    int node = i/90, f = i - node*90;
    H[node*HF + f] = f32f ? f2bf(xf[(nb + node)*90 + f]) : x[(nb + node)*90 + f];
  }
  for (int i = tid; i < NNODES*6; i += 512) {
    int node = i/6, c = i - node*6;
    H[node*HF + 90 + c] = 0;
  }
  __syncthreads();

#pragma unroll
  for (int l = 0; l < 3; ++l) {
    const unsigned short* wpk  = (l==0)? w1p : (l==1)? w2p : w3p;
    const unsigned short* bias = (l==0)? b1 : (l==1)? b2 : b3;
    const int nK = (l==0)? 3 : 4;

    // mm1: Tt = (H @ W)^T.  wave owns nt = wave.
    {
      const int nt = wave;
      for (int mt = 0; mt < 6; ++mt) {
        int row = mt*16 + r; if (row > 89) row = 89;  // clamp; killed by A's zero cols
        fx4 acc = {0.f,0.f,0.f,0.f};
#pragma unroll
        for (int ks = 0; ks < 4; ++ks)
          if (ks < nK) {
            bfx8 af = *(const bfx8*)(const void*)&H[row*HF + ks*32 + q*8];
            bfx8 bf = *(const bfx8*)(const void*)&wpk[((nt*nK + ks)*64 + lane)*8];
            acc = __builtin_amdgcn_mfma_f32_16x16x32_bf16(af, bf, acc, 0,0,0);
          }
        us4 o;
#pragma unroll
        for (int i2=0;i2<4;i2++) o[i2] = f2bf(acc[i2]);
        // D[node=q*4+i][feat=r] -> Tt[feat][node]
        *(us4*)&Tt[(nt*16 + r)*NPAD + mt*16 + q*4] = o;
      }
    }
    __syncthreads();

    // agg: H = relu(A@T + b) via S^T = T^T @ A^T.  wave owns ft = wave.
    {
      const int ft = wave;
      bfx8 af[3];
#pragma unroll
      for (int ks = 0; ks < 3; ++ks)
        af[ks] = *(const bfx8*)(const void*)&Tt[(ft*16 + r)*NPAD + ks*32 + q*8];
      float bv[4];
#pragma unroll
      for (int i2=0;i2<4;i2++){
        int bidx = ft*16 + q*4 + i2;
        bv[i2] = f32f ? ((const float*)bias)[bidx] : bf2f(bias[bidx]);
      }
      for (int nt = 0; nt < 6; ++nt) {
        int arow = nt*16 + r; if (arow > 89) arow = 89;
        fx4 acc = {0.f,0.f,0.f,0.f};
#pragma unroll
        for (int ks = 0; ks < 3; ++ks) {
          bfx8 bfr = *(const bfx8*)(const void*)&Abf[arow*NPAD + ks*32 + q*8];
          acc = __builtin_amdgcn_mfma_f32_16x16x32_bf16(af[ks], bfr, acc, 0,0,0);
        }
        int m = nt*16 + r;                  // node
        if (m < NNODES) {
          us4 o;
#pragma unroll
          for (int i2=0;i2<4;i2++){
            float v = acc[i2] + bv[i2];
            o[i2] = f2bf(v > 0.f ? v : 0.f);
          }
          *(us4*)&H[m*HF + ft*16 + q*4] = o;
        }
      }
    }
    __syncthreads();

    // stream H -> xc[:, l*128 : (l+1)*128]
    for (int i = tid*4; i < NNODES*HF; i += 512*4) {
      us4 v = *(const us4*)&H[i];
      int node = i >> 7, f = i & 127;
      *(us4*)&xc[(nb + node)*384 + l*128 + f] = v;
    }
    __syncthreads();
  }
}

// ---- head GEMM: [512,34560]@[34560,64], split-K=45, 128-k staging per barrier
__global__ __launch_bounds__(256) void gemm2_kern(
    const unsigned short* __restrict__ z,   // xc viewed as [512][34560]
    const unsigned short* __restrict__ wp,  // packed lin1_W
    float* __restrict__ accf)               // [512][64]
{
  __shared__ __align__(16) unsigned short zt[32*128];  // [32 rows][128 k], swizzled 16B chunks
  int mb = blockIdx.x % 16;
  int kb = blockIdx.x / 16;
  int tid = threadIdx.x;
  int lane = tid & 63, wave = tid >> 6;
  int q = lane >> 4, r = lane & 15;
  int mt = wave >> 1;            // 0..1
  int nt0 = (wave & 1)*2;        // 0 or 2
  int m0 = mb*32;

  fx4 acc0 = {0,0,0,0}, acc1 = {0,0,0,0};
  int Lm = tid >> 3, Lc = tid & 7;
  int cA = Lc ^ (Lm & 7);        // source chunk stored at position Lc
  int arow = mt*16 + r;

  for (int it = 0; it < KSTEPS/4; ++it) {   // 6 iters x 128 k
    int ks0 = kb*KSTEPS + it*4;
    int kbase = ks0*32;
    {
      us8 vA = *(const us8*)&z[(m0+Lm)*KTOT + kbase + cA*8];
      us8 vB = *(const us8*)&z[(m0+Lm)*KTOT + kbase + (cA+8)*8];
      *(us8*)&zt[Lm*128 + Lc*8] = vA;
      *(us8*)&zt[Lm*128 + (Lc+8)*8] = vB;
    }
    __syncthreads();
#pragma unroll
    for (int ks2 = 0; ks2 < 4; ++ks2) {
      int c = ks2*4 + q;                       // k-chunk 0..15
      int pos = (c & 8) | ((c & 7) ^ (arow & 7));
      bfx8 af = *(const bfx8*)(const void*)&zt[arow*128 + pos*8];
      int ksg = ks0 + ks2;
      bfx8 bA = *(const bfx8*)(const void*)&wp[(((nt0+0)*NKTOT + ksg)*64 + lane)*8];
      bfx8 bB = *(const bfx8*)(const void*)&wp[(((nt0+1)*NKTOT + ksg)*64 + lane)*8];
      acc0 = __builtin_amdgcn_mfma_f32_16x16x32_bf16(af, bA, acc0, 0,0,0);
      acc1 = __builtin_amdgcn_mfma_f32_16x16x32_bf16(af, bB, acc1, 0,0,0);
    }
    __syncthreads();
  }
#pragma unroll
  for (int i2 = 0; i2 < 4; ++i2) {
    int row = m0 + mt*16 + q*4 + i2;
    atomicAdd(&accf[row*64 + (nt0+0)*16 + r], acc0[i2]);
    atomicAdd(&accf[row*64 + (nt0+1)*16 + r], acc1[i2]);
  }
}

// ---- head: wave per graph; bias+relu, lin2, log_softmax (C=2)
__global__ void head_kern(const float* __restrict__ accf,
                          const unsigned short* __restrict__ l1b,
                          const unsigned short* __restrict__ l2w,
                          const unsigned short* __restrict__ l2b,
                          unsigned short* __restrict__ out,
                          const int* __restrict__ flags)
{
  int gph = blockIdx.x;
  int j = threadIdx.x;               // 64
  const int f32f = flags[0];
  const float* l1bf = (const float*)l1b;
  const float* l2wf = (const float*)l2w;
  const float* l2bf = (const float*)l2b;
  float h = accf[gph*64 + j] + (f32f ? l1bf[j] : bf2f(l1b[j]));
  h = h > 0.f ? h : 0.f;
  float p0 = h * (f32f ? l2wf[2*j]   : bf2f(l2w[2*j]));
  float p1 = h * (f32f ? l2wf[2*j+1] : bf2f(l2w[2*j+1]));
  for (int off = 32; off; off >>= 1) {
    p0 += __shfl_down(p0, off);
    p1 += __shfl_down(p1, off);
  }
  if (j == 0) {
    float l0 = p0 + (f32f ? l2bf[0] : bf2f(l2b[0]));
    float l1 = p1 + (f32f ? l2bf[1] : bf2f(l2b[1]));
    float mx = fmaxf(l0, l1);
    float lse = mx + logf(expf(l0-mx) + expf(l1-mx));
    if (f32f) {
      ((float*)out)[gph*2]   = l0 - lse;
      ((float*)out)[gph*2+1] = l1 - lse;
    } else {
      out[gph*2]   = f2bf(l0 - lse);
      out[gph*2+1] = f2bf(l1 - lse);
    }
  }
}

extern "C" void kernel_launch(void* const* d_in, const int* in_sizes, int n_in,
                              void* d_out, int out_size, void* d_ws, size_t ws_size,
                              hipStream_t stream)
{
  const unsigned short* x   = (const unsigned short*)d_in[0];
  const unsigned short* ea  = (const unsigned short*)d_in[1];
  const unsigned short* W1  = (const unsigned short*)d_in[2];
  const unsigned short* b1  = (const unsigned short*)d_in[3];
  const unsigned short* W2  = (const unsigned short*)d_in[4];
  const unsigned short* b2  = (const unsigned short*)d_in[5];
  const unsigned short* W3  = (const unsigned short*)d_in[6];
  const unsigned short* b3  = (const unsigned short*)d_in[7];
  const unsigned short* L1W = (const unsigned short*)d_in[8];
  const unsigned short* L1b = (const unsigned short*)d_in[9];
  const unsigned short* L2W = (const unsigned short*)d_in[10];
  const unsigned short* L2b = (const unsigned short*)d_in[11];
  const int* ei             = (const int*)d_in[12];
  unsigned short* out       = (unsigned short*)d_out;

  char* ws = (char*)d_ws;
  unsigned short* xc  = (unsigned short*)(ws);             // 35,389,440 B
  unsigned short* l1p = (unsigned short*)(ws + 35389440);  //  4,423,680 B
  unsigned short* w1p = (unsigned short*)(ws + 39813120);  //     24,576 B
  unsigned short* w2p = (unsigned short*)(ws + 39837696);  //     32,768 B
  unsigned short* w3p = (unsigned short*)(ws + 39870464);  //     32,768 B
  float* accf         = (float*)(ws + 39903232);           //    131,072 B
  int* flags          = (int*)(ws + 40034304);             //        256 B

  probe_kern<<<1, 256, 0, stream>>>(x, ei, flags);
  pack_w3_kern<<<22, 256, 0, stream>>>(W1, W2, W3, w1p, w2p, w3p, flags);
  pack_lin1_kern<<<NKTOT, 256, 0, stream>>>(L1W, l1p, flags);
  gcn_layers_kern<<<NGRAPH, 512, 0, stream>>>(x, ea, ei, w1p, w2p, w3p,
                                              b1, b2, b3, xc, flags);
  hipMemsetAsync(accf, 0, NGRAPH*64*sizeof(float), stream);
  gemm2_kern<<<16*KSPLIT, 256, 0, stream>>>(xc, l1p, accf);
  head_kern<<<NGRAPH, 64, 0, stream>>>(accf, L1b, L2W, L2b, out, flags);
}

// Round 5
// 143.905 us; speedup vs baseline: 1.6252x; 1.1921x over previous
//
#include <hip/hip_runtime.h>

typedef __bf16 bfx8 __attribute__((ext_vector_type(8)));
typedef float fx4 __attribute__((ext_vector_type(4)));
typedef unsigned short us4 __attribute__((ext_vector_type(4)));
typedef unsigned short us8 __attribute__((ext_vector_type(8)));

#define NNODES 90
#define NPAD   96
#define HF     128
#define NGRAPH 512
#define EPG    1440                 // edges per graph
#define ETOT   (NGRAPH*EPG)
#define KTOT   34560                // 90*384
#define NKTOT  1080                 // KTOT/32
#define KSPLIT 45
#define KSTEPS (NKTOT/KSPLIT)       // 24

__device__ __forceinline__ unsigned short f2bf(float f){
  union { float f; unsigned u; } v; v.f = f;
  return (unsigned short)((v.u + 0x7FFFu + ((v.u>>16)&1u)) >> 16);
}
// H is stored with 16B-chunk XOR swizzle: elem (node,f) lives at
//   node*128 + ((f>>3) ^ (node&15))*8 + (f&7)
__device__ __forceinline__ int hsw(int node, int f){
  return node*HF + ((((f>>3) ^ (node&15)))<<3) + (f&7);
}

// ---- one kernel: pack lin1_W (blocks 0..1079), pack W1/W2/W3 (1080..1101),
//      zero accf (1102..1103).  All weights are f32 in; bf16 frags out.
__global__ __launch_bounds__(256) void pack_all_kern(
    const float* __restrict__ W1,
    const float* __restrict__ W2,
    const float* __restrict__ W3,
    const float* __restrict__ L1W,
    unsigned short* __restrict__ o1,
    unsigned short* __restrict__ o2,
    unsigned short* __restrict__ o3,
    unsigned short* __restrict__ l1p,
    float* __restrict__ accf)
{
  __shared__ __align__(16) unsigned short tile[32*64];
  int b = blockIdx.x;
  int t = threadIdx.x;
  if (b < NKTOT) {                 // ---- lin1 pack: [34560][64] f32 -> frag layout
    int ks = b;
#pragma unroll
    for (int j=0;j<8;j++) tile[t*8+j] = f2bf(L1W[ks*32*64 + t*8 + j]);
    __syncthreads();
    int lane = t & 63;
    int nt = t >> 6;
    int n  = nt*16 + (lane&15);
    int kq = (lane>>4)*8;
    us8 v;
#pragma unroll
    for (int j=0;j<8;j++) v[j] = tile[(kq+j)*64 + n];
    *(us8*)&l1p[((nt*NKTOT + ks)*64 + lane)*8] = v;
  } else if (b < NKTOT + 22) {     // ---- conv weight pack
    int bb = b - NKTOT;
    const float* W; unsigned short* out; int K, nK, tt;
    if (bb < 6)       { W = W1; out = o1; K = 90;  nK = 3; tt = bb*256 + t; }
    else if (bb < 14) { W = W2; out = o2; K = 128; nK = 4; tt = (bb-6)*256 + t; }
    else              { W = W3; out = o3; K = 128; nK = 4; tt = (bb-14)*256 + t; }
    int lane = tt & 63;
    int ks = (tt>>6) % nK;
    int nt = (tt>>6) / nK;
    int n  = nt*16 + (lane&15);
    int k0 = ks*32 + (lane>>4)*8;
    unsigned short v[8];
#pragma unroll
    for (int j=0;j<8;j++){ int k=k0+j; v[j] = (k<K)? f2bf(W[k*128+n]) : (unsigned short)0; }
    unsigned short* o = out + ((nt*nK+ks)*64 + lane)*8;
#pragma unroll
    for (int j=0;j<8;j++) o[j]=v[j];
  } else {                         // ---- zero accf [512*64 floats]
    int base = (b - (NKTOT+22))*16384 + t*4;
#pragma unroll
    for (int i = 0; i < 16; ++i) {
      fx4 z = {0.f,0.f,0.f,0.f};
      *(fx4*)&accf[base + i*1024] = z;
    }
  }
}

// ---- per-graph GCN, 512 threads (8 waves).
// LDS: Abf[90][96]bf16 @0 | H[90][128]bf16 (swizzled) @17280 | Tt[128][96]bf16 @40320
//      Af[90][96]f32 @17280 (phase0, overlaps H/Tt) | deg[96]f32 @64896
__global__ __launch_bounds__(512) void gcn_layers_kern(
    const float* __restrict__ x,
    const float* __restrict__ eattr,
    const int* __restrict__ ei,
    const unsigned short* __restrict__ w1p,
    const unsigned short* __restrict__ w2p,
    const unsigned short* __restrict__ w3p,
    const float* __restrict__ b1,
    const float* __restrict__ b2,
    const float* __restrict__ b3,
    unsigned short* __restrict__ xc)
{
  __shared__ __align__(16) char smem[65280];
  unsigned short* Abf = (unsigned short*)smem;
  unsigned short* H   = (unsigned short*)(smem + 17280);
  unsigned short* Tt  = (unsigned short*)(smem + 40320);
  float* Af  = (float*)(smem + 17280);
  float* deg = (float*)(smem + 64896);

  const int g = blockIdx.x;
  const int tid = threadIdx.x;
  const int lane = tid & 63, wave = tid >> 6;
  const int q = lane >> 4, r = lane & 15;
  const int eb = g*EPG;
  const int nb = g*NNODES;
  const long long* e64 = (const long long*)ei;

  // int-width detection (wave-uniform): i64 storage -> odd int32 words of the
  // first 64 entries are high words of small values == 0; i32 -> node ids != 0.
  bool i64f;
  {
    int v = ei[2*lane + 1];
    i64f = (__ballot(v != 0) == 0ull);
  }

  // ---- phase 0: edge prefetch into regs, zero Af/deg, one atomic pass,
  //      separable normalization at conversion.
  const int e0 = tid, e1 = tid + 512, e2 = tid + 1024;
  const bool h2 = (e2 < EPG);
  int s0, d0, s1, d1, s2 = nb, d2 = nb;
  if (i64f) {
    s0 = (int)e64[eb+e0]; d0 = (int)e64[ETOT+eb+e0];
    s1 = (int)e64[eb+e1]; d1 = (int)e64[ETOT+eb+e1];
    if (h2) { s2 = (int)e64[eb+e2]; d2 = (int)e64[ETOT+eb+e2]; }
  } else {
    s0 = ei[eb+e0]; d0 = ei[ETOT+eb+e0];
    s1 = ei[eb+e1]; d1 = ei[ETOT+eb+e1];
    if (h2) { s2 = ei[eb+e2]; d2 = ei[ETOT+eb+e2]; }
  }
  float w0 = eattr[eb+e0];
  float w1 = eattr[eb+e1];
  float w2 = h2 ? eattr[eb+e2] : 0.f;

  for (int i = tid; i < NPAD; i += 512) deg[i] = 1.0f;     // self-loop weight
  for (int i = tid; i < NNODES*NPAD; i += 512) Af[i] = 0.0f;
  __syncthreads();
  atomicAdd(&Af[(d0-nb)*NPAD + (s0-nb)], w0); atomicAdd(&deg[d0-nb], w0);
  atomicAdd(&Af[(d1-nb)*NPAD + (s1-nb)], w1); atomicAdd(&deg[d1-nb], w1);
  if (h2) { atomicAdd(&Af[(d2-nb)*NPAD + (s2-nb)], w2); atomicAdd(&deg[d2-nb], w2); }
  __syncthreads();
  for (int i = tid; i < NPAD; i += 512) deg[i] = rsqrtf(deg[i]);  // deg>=1
  __syncthreads();
  for (int i = tid; i < NNODES*NPAD; i += 512) {
    int row = i / NPAD, col = i - row*NPAD;
    float a = Af[i];
    if (col == row) a += 1.0f;                    // self-loop
    Abf[i] = f2bf(a * deg[row] * deg[col]);       // pad cols: Af=0 -> Abf=0
  }
  __syncthreads();
  // load X (f32) into swizzled bf16 H (cols 90..95 zeroed: NaN-safe K-pad)
  for (int i = tid; i < NNODES*90; i += 512) {
    int node = i/90, f = i - node*90;
    H[hsw(node, f)] = f2bf(x[(nb + node)*90 + f]);
  }
  for (int i = tid; i < NNODES*6; i += 512) {
    int node = i/6, f = 90 + (i - node*6);
    H[hsw(node, f)] = 0;
  }
  __syncthreads();

#pragma unroll
  for (int l = 0; l < 3; ++l) {
    const unsigned short* wpk = (l==0)? w1p : (l==1)? w2p : w3p;
    const float* bias         = (l==0)? b1 : (l==1)? b2 : b3;
    const int nK = (l==0)? 3 : 4;

    // hoisted B-frags for mm1 (nt = wave)
    bfx8 wf[4];
#pragma unroll
    for (int ks = 0; ks < 4; ++ks)
      if (ks < nK) wf[ks] = *(const bfx8*)(const void*)&wpk[((wave*nK + ks)*64 + lane)*8];

    // mm1: Tt = (H @ W)^T, wave owns nt = wave
    for (int mt = 0; mt < 6; ++mt) {
      int row = mt*16 + r; if (row > 89) row = 89;  // clamp; killed by A's zero cols
      fx4 acc = {0.f,0.f,0.f,0.f};
#pragma unroll
      for (int ks = 0; ks < 4; ++ks)
        if (ks < nK) {
          bfx8 af = *(const bfx8*)(const void*)&H[row*HF + (((4*ks + q) ^ (row&15))<<3)];
          acc = __builtin_amdgcn_mfma_f32_16x16x32_bf16(af, wf[ks], acc, 0,0,0);
        }
      us4 o;
#pragma unroll
      for (int i2=0;i2<4;i2++) o[i2] = f2bf(acc[i2]);
      *(us4*)&Tt[(wave*16 + r)*NPAD + mt*16 + q*4] = o;
    }
    __syncthreads();

    // agg: H = relu(A@T + b) via S^T = T^T @ A^T, wave owns ft = wave
    {
      bfx8 tf[3];
#pragma unroll
      for (int ks = 0; ks < 3; ++ks)
        tf[ks] = *(const bfx8*)(const void*)&Tt[(wave*16 + r)*NPAD + ks*32 + q*8];
      float bv[4];
#pragma unroll
      for (int i2=0;i2<4;i2++) bv[i2] = bias[wave*16 + q*4 + i2];
      for (int nt = 0; nt < 6; ++nt) {
        int arow = nt*16 + r; if (arow > 89) arow = 89;
        fx4 acc = {0.f,0.f,0.f,0.f};
#pragma unroll
        for (int ks = 0; ks < 3; ++ks) {
          bfx8 bfr = *(const bfx8*)(const void*)&Abf[arow*NPAD + ks*32 + q*8];
          acc = __builtin_amdgcn_mfma_f32_16x16x32_bf16(tf[ks], bfr, acc, 0,0,0);
        }
        int m = nt*16 + r;                  // node
        if (m < NNODES) {
          us4 o;
#pragma unroll
          for (int i2=0;i2<4;i2++){
            float v = acc[i2] + bv[i2];
            o[i2] = f2bf(v > 0.f ? v : 0.f);
          }
          // feats f0 = wave*16 + q*4 : chunk = 2*wave + (q>>1), offset (q&1)*4
          *(us4*)&H[m*HF + (((2*wave + (q>>1)) ^ (m&15))<<3) + (q&1)*4] = o;
        }
      }
    }
    __syncthreads();

    // stream H -> xc[:, l*128 : (l+1)*128] (reads only; next layer's barrier fences)
    for (int i = tid*4; i < NNODES*HF; i += 512*4) {
      int node = i >> 7, f = i & 127;
      us4 v = *(const us4*)&H[node*HF + (((f>>3) ^ (node&15))<<3) + (f&7)];
      *(us4*)&xc[(nb + node)*384 + l*128 + f] = v;
    }
  }
}

// ---- head GEMM: [512,34560]@[34560,64], split-K=45, z-tile register prefetch
__global__ __launch_bounds__(256) void gemm2_kern(
    const unsigned short* __restrict__ z,   // xc viewed as [512][34560] bf16
    const unsigned short* __restrict__ wp,  // packed lin1_W bf16
    float* __restrict__ accf)               // [512][64]
{
  __shared__ __align__(16) unsigned short zt[32*128];  // [32 rows][128 k], swizzled 16B chunks
  int mb = blockIdx.x % 16;
  int kb = blockIdx.x / 16;
  int tid = threadIdx.x;
  int lane = tid & 63, wave = tid >> 6;
  int q = lane >> 4, r = lane & 15;
  int mt = wave >> 1;            // 0..1
  int nt0 = (wave & 1)*2;        // 0 or 2
  int m0 = mb*32;

  fx4 acc0 = {0,0,0,0}, acc1 = {0,0,0,0};
  int Lm = tid >> 3, Lc = tid & 7;
  int cA = Lc ^ (Lm & 7);        // source chunk stored at position Lc
  int arow = mt*16 + r;
  const unsigned short* zrow = &z[(m0+Lm)*KTOT];

  us8 pvA = *(const us8*)&zrow[kb*KSTEPS*32 + cA*8];
  us8 pvB = *(const us8*)&zrow[kb*KSTEPS*32 + (cA+8)*8];

  for (int it = 0; it < KSTEPS/4; ++it) {   // 6 iters x 128 k
    *(us8*)&zt[Lm*128 + Lc*8] = pvA;
    *(us8*)&zt[Lm*128 + (Lc+8)*8] = pvB;
    __syncthreads();
    if (it < KSTEPS/4 - 1) {
      int kn = (kb*KSTEPS + (it+1)*4)*32;
      pvA = *(const us8*)&zrow[kn + cA*8];
      pvB = *(const us8*)&zrow[kn + (cA+8)*8];
    }
    int ks0 = kb*KSTEPS + it*4;
#pragma unroll
    for (int ks2 = 0; ks2 < 4; ++ks2) {
      int c = ks2*4 + q;                       // k-chunk 0..15
      int pos = (c & 8) | ((c & 7) ^ (arow & 7));
      bfx8 af = *(const bfx8*)(const void*)&zt[arow*128 + pos*8];
      int ksg = ks0 + ks2;
      bfx8 bA = *(const bfx8*)(const void*)&wp[(((nt0+0)*NKTOT + ksg)*64 + lane)*8];
      bfx8 bB = *(const bfx8*)(const void*)&wp[(((nt0+1)*NKTOT + ksg)*64 + lane)*8];
      acc0 = __builtin_amdgcn_mfma_f32_16x16x32_bf16(af, bA, acc0, 0,0,0);
      acc1 = __builtin_amdgcn_mfma_f32_16x16x32_bf16(af, bB, acc1, 0,0,0);
    }
    __syncthreads();
  }
#pragma unroll
  for (int i2 = 0; i2 < 4; ++i2) {
    int row = m0 + mt*16 + q*4 + i2;
    atomicAdd(&accf[row*64 + (nt0+0)*16 + r], acc0[i2]);
    atomicAdd(&accf[row*64 + (nt0+1)*16 + r], acc1[i2]);
  }
}

// ---- head: wave per graph (4 graphs/block); bias+relu, lin2, log_softmax; f32 out
__global__ __launch_bounds__(256) void head_kern(
    const float* __restrict__ accf,
    const float* __restrict__ l1b,
    const float* __restrict__ l2w,
    const float* __restrict__ l2b,
    float* __restrict__ out)
{
  int gph = blockIdx.x*4 + (threadIdx.x >> 6);
  int j = threadIdx.x & 63;
  float h = accf[gph*64 + j] + l1b[j];
  h = h > 0.f ? h : 0.f;
  float p0 = h * l2w[2*j];
  float p1 = h * l2w[2*j+1];
  for (int off = 32; off; off >>= 1) {
    p0 += __shfl_down(p0, off);
    p1 += __shfl_down(p1, off);
  }
  if (j == 0) {
    float l0 = p0 + l2b[0];
    float l1 = p1 + l2b[1];
    float mx = fmaxf(l0, l1);
    float lse = mx + logf(expf(l0-mx) + expf(l1-mx));
    out[gph*2]   = l0 - lse;
    out[gph*2+1] = l1 - lse;
  }
}

extern "C" void kernel_launch(void* const* d_in, const int* in_sizes, int n_in,
                              void* d_out, int out_size, void* d_ws, size_t ws_size,
                              hipStream_t stream)
{
  const float* x   = (const float*)d_in[0];
  const float* ea  = (const float*)d_in[1];
  const float* W1  = (const float*)d_in[2];
  const float* b1  = (const float*)d_in[3];
  const float* W2  = (const float*)d_in[4];
  const float* b2  = (const float*)d_in[5];
  const float* W3  = (const float*)d_in[6];
  const float* b3  = (const float*)d_in[7];
  const float* L1W = (const float*)d_in[8];
  const float* L1b = (const float*)d_in[9];
  const float* L2W = (const float*)d_in[10];
  const float* L2b = (const float*)d_in[11];
  const int* ei    = (const int*)d_in[12];
  float* out       = (float*)d_out;

  char* ws = (char*)d_ws;
  unsigned short* xc  = (unsigned short*)(ws);             // 35,389,440 B
  unsigned short* l1p = (unsigned short*)(ws + 35389440);  //  4,423,680 B
  unsigned short* w1p = (unsigned short*)(ws + 39813120);  //     24,576 B
  unsigned short* w2p = (unsigned short*)(ws + 39837696);  //     32,768 B
  unsigned short* w3p = (unsigned short*)(ws + 39870464);  //     32,768 B
  float* accf         = (float*)(ws + 39903232);           //    131,072 B

  pack_all_kern<<<NKTOT + 22 + 2, 256, 0, stream>>>(W1, W2, W3, L1W,
                                                    w1p, w2p, w3p, l1p, accf);
  gcn_layers_kern<<<NGRAPH, 512, 0, stream>>>(x, ea, ei, w1p, w2p, w3p,
                                              b1, b2, b3, xc);
  gemm2_kern<<<16*KSPLIT, 256, 0, stream>>>(xc, l1p, accf);
  head_kern<<<NGRAPH/4, 256, 0, stream>>>(accf, L1b, L2W, L2b, out);
}